// Round 15
// baseline (21.557 us; speedup 1.0000x reference)
//
#include <hip/hip_runtime.h>
#include <hip/hip_fp16.h>

// N=4096, M=128, R=16, W=64, NG=1024, delta = 1/128 exactly.
// out[n,r,w] = sum_m red[n,r,m] * poly5(x0; coeff[idx,:,w])
// Approx: degree-1 + x0 sub-binned to 4 centers per cell:
//   tbl2[ii][w] = f16(c4[ii>>2][w]*(2*(ii&3)+1)/1024 + c5[ii>>2][w]), ii=(int)(x*512)
// This round: full-line output stores via LDS transpose (obuf aliases dead eT,
// stride-68 padding) + full-GPU prepass (256 blocks, uint2/thread).

constexpr int MM = 128;
constexpr int RR = 16;
constexpr int WW = 64;
constexpr int NG = 1024;
constexpr int NROW = NG * 4;   // 4096 sub-binned rows

using f32x4 = __attribute__((ext_vector_type(4))) float;
using f16x8 = __attribute__((ext_vector_type(8))) _Float16;

__device__ __forceinline__ unsigned pk_f16(float lo, float hi) {
    auto h = __builtin_amdgcn_cvt_pkrtz(lo, hi);      // v_cvt_pkrtz_f16_f32
    unsigned r; __builtin_memcpy(&r, &h, 4); return r;
}

// ---- prepass: 256 blocks x 256 threads, uint2 (4 w's) per thread ----
__global__ __launch_bounds__(256)
void build_tbl2_kernel(const float* __restrict__ poly, unsigned* __restrict__ tbl) {
    const int t  = blockIdx.x * 256 + threadIdx.x;    // 65536
    const int g2 = t >> 4;          // fine row 0..4095
    const int wq = t & 15;          // w-quad: w = wq*4 .. +3
    const int g  = g2 >> 2;
    const int s  = g2 & 3;
    const float x0c = (float)(2 * s + 1) * (1.0f / 1024.0f);
    const float* p = poly + (size_t)g * 384 + wq * 4;
    const float4 c4 = *(const float4*)(p + 256);
    const float4 c5 = *(const float4*)(p + 320);
    uint2 v;
    v.x = pk_f16(fmaf(c4.x, x0c, c5.x), fmaf(c4.y, x0c, c5.y));
    v.y = pk_f16(fmaf(c4.z, x0c, c5.z), fmaf(c4.w, x0c, c5.w));
    *(uint2*)(tbl + (size_t)g2 * 32 + wq * 2) = v;
}

template<bool USE_TBL>
__global__ __launch_bounds__(256, 8)
void embed_mfma_kernel(const float* __restrict__ x,
                       const unsigned* __restrict__ tbl,
                       const float* __restrict__ poly,
                       const float* __restrict__ red,
                       float* __restrict__ out)
{
    // rows of 128 f16 = 16 uint4 blocks, block idx swizzled ^ (row&7)
    __shared__ uint4 eT[WW][16];   // 16 KB (aliased as obuf in epilogue)
    __shared__ uint4 rA[RR][16];   //  4 KB  -> 20 KB total

    const int n   = blockIdx.x;
    const int t   = threadIdx.x;
    const int c16 = t & 15;
    const int mq  = t >> 4;        // 0..15: owned m-block (8 m's)
    const int q   = mq & 3;        // lane>>4
    const int wt  = t >> 6;

    // ---- x first (heads the serial chain x -> idx -> gather) ----
    const float* xp = x + (size_t)n * MM + mq * 8;
    const float4 xa = *(const float4*)xp;
    const float4 xb = *(const float4*)(xp + 4);
    // ---- red second (latency hides under gather issue/processing) ----
    const float4* rv = (const float4*)(red + (size_t)n * (RR * MM));
    const float4 ra = rv[2 * t];
    const float4 rb = rv[2 * t + 1];

    const float xs[8] = {xa.x, xa.y, xa.z, xa.w, xb.x, xb.y, xb.z, xb.w};

    uint2 g[8];   // lane's 4 w's (w = c16*4..+3) for m = mq*8 + j
    if (USE_TBL) {
        const char* tb = (const char*)tbl + c16 * 8;
#pragma unroll
        for (int j = 0; j < 8; ++j) {
            // exact: &~127 of (int)(x*65536) == floor(x*512)*128 (row byte offset)
            const int off = ((int)(xs[j] * 65536.0f)) & 0xFFFFFF80;
            g[j] = *(const uint2*)(tb + off);
        }
    } else {
#pragma unroll
        for (int j = 0; j < 8; ++j) {
            const int ii = (int)(xs[j] * 512.0f);
            const int ic = ii >> 2;
            const float x0 = xs[j] - (float)ic * 0.0078125f;
            const float* pc = poly + (size_t)ic * 384 + c16 * 4;
            const float4 c4 = *(const float4*)(pc + 256);
            const float4 c5 = *(const float4*)(pc + 320);
            g[j].x = pk_f16(fmaf(c4.x, x0, c5.x), fmaf(c4.y, x0, c5.y));
            g[j].y = pk_f16(fmaf(c4.z, x0, c5.z), fmaf(c4.w, x0, c5.w));
        }
    }

    // ---- rA stage (thread holds red row mq, cols c16*8..+7) ----
    {
        uint4 rp;
        rp.x = pk_f16(ra.x, ra.y); rp.y = pk_f16(ra.z, ra.w);
        rp.z = pk_f16(rb.x, rb.y); rp.w = pk_f16(rb.z, rb.w);
        rA[mq][c16 ^ (mq & 7)] = rp;
    }

    // ---- eT stage: v_perm repack (m-pair per u32), zero arithmetic ----
#pragma unroll
    for (int c = 0; c < 4; ++c) {
        const int w   = c16 * 4 + c;
        const unsigned sel = (c & 1) ? 0x07060302u : 0x05040100u;
        unsigned e[4];
#pragma unroll
        for (int p = 0; p < 4; ++p) {
            const unsigned gl = (c >> 1) ? g[2 * p].y     : g[2 * p].x;
            const unsigned gh = (c >> 1) ? g[2 * p + 1].y : g[2 * p + 1].x;
            e[p] = __builtin_amdgcn_perm(gh, gl, sel);   // (e[2p+1,w]<<16)|e[2p,w]
        }
        uint4 v; v.x = e[0]; v.y = e[1]; v.z = e[2]; v.w = e[3];
        eT[w][mq ^ (w & 7)] = v;
    }

    __syncthreads();

    // ---- MFMA: wave wt -> out[n][0:16][wt*16..+16], K=128 as 4x 16x16x32 ----
    const int sa   = c16 & 7;
    const int rowb = wt * 16 + c16;          // rowb&7 == sa
    f32x4 acc = {0.f, 0.f, 0.f, 0.f};
#pragma unroll
    for (int kc = 0; kc < 4; ++kc) {
        const int bk = kc * 4 + q;
        const uint4 av = rA[c16][bk ^ sa];
        const uint4 bv = eT[rowb][bk ^ sa];
        f16x8 af, bf;
        __builtin_memcpy(&af, &av, 16);
        __builtin_memcpy(&bf, &bv, 16);
        acc = __builtin_amdgcn_mfma_f32_16x16x32_f16(af, bf, acc, 0, 0, 0);
    }

    // ---- epilogue: transpose via LDS (alias dead eT), full-line stores ----
    __syncthreads();                          // all rA/eT reads complete
    float* obuf = (float*)eT;                 // [16 rows][stride 68] floats
    // scalar writes: bank = (16q + 4reg + 16wt + c16) % 32 -> 2 lanes/bank (free)
#pragma unroll
    for (int reg = 0; reg < 4; ++reg)
        obuf[(q * 4 + reg) * 68 + rowb] = acc[reg];
    __syncthreads();
    // coalesced store: thread t -> row t>>4, w-quad t&15; per wave 1KB = 8 full lines
    const int orow = t >> 4, owq = t & 15;
    const float4 ov = *(const float4*)(obuf + orow * 68 + owq * 4);
    *(float4*)(out + (size_t)n * (RR * WW) + orow * WW + owq * 4) = ov;
}

extern "C" void kernel_launch(void* const* d_in, const int* in_sizes, int n_in,
                              void* d_out, int out_size, void* d_ws, size_t ws_size,
                              hipStream_t stream) {
    const float* x    = (const float*)d_in[0];
    const float* poly = (const float*)d_in[1];
    const float* red  = (const float*)d_in[2];
    float* out = (float*)d_out;
    const int N = in_sizes[0] / MM;   // 4096

    if (ws_size >= (size_t)NROW * 32 * sizeof(unsigned)) {
        unsigned* tbl = (unsigned*)d_ws;
        build_tbl2_kernel<<<(NROW * 16) / 256, 256, 0, stream>>>(poly, tbl);
        embed_mfma_kernel<true><<<N, 256, 0, stream>>>(x, tbl, poly, red, out);
    } else {
        embed_mfma_kernel<false><<<N, 256, 0, stream>>>(x, nullptr, poly, red, out);
    }
}